// Round 22
// baseline (63.257 us; speedup 1.0000x reference)
//
#include <hip/hip_runtime.h>

#define NF 40
#define KD 64

typedef float f32x4 __attribute__((ext_vector_type(4)));
typedef float f32x16 __attribute__((ext_vector_type(16)));
typedef _Float16 f16x8 __attribute__((ext_vector_type(8)));
typedef _Float16 f16x4 __attribute__((ext_vector_type(4)));

__global__ __launch_bounds__(256, 4)
void afm_kernel(const int* __restrict__ x,
                const float* __restrict__ lin_table,
                const float* __restrict__ V_table,
                const float* __restrict__ W1,
                const float* __restrict__ b1,
                const float* __restrict__ W2,
                const float* __restrict__ b2,
                const float* __restrict__ Wf,
                const float* __restrict__ bf,
                float* __restrict__ out)
{
    // all tiles stride 72 f16 = 144 B (16B-aligned rows, 4-bank/row rotation)
    __shared__ _Float16 e16[NF][72];     // embeddings [field][k]
    __shared__ _Float16 eT16[KD][72];    // transposed [k][field]; cols 40..71 zero
    __shared__ _Float16 Q16[48][72];     // exp(score); fully zero-init (NaN safety)
    __shared__ unsigned short lut[832];  // p -> (i<<8|j); 832 = 26 tiles x 32
    __shared__ float wsum[4];

    const int b = blockIdx.x;
    const int tid = threadIdx.x;
    const int w = tid >> 6;
    const int lane = tid & 63;
    const int l15 = lane & 15;
    const int lhi = lane >> 4;
    const int l31 = lane & 31;
    const int h5 = lane >> 5;            // k-half for 32x32 fragments

    // ---- zero-init: ALL of Q16 (MFMA A-side NaN safety), eT16 cols 40..71
    {
        f16x8 zh = {0, 0, 0, 0, 0, 0, 0, 0};
        for (int t = tid; t < 48 * 72 / 8; t += 256)
            reinterpret_cast<f16x8*>(&Q16[0][0])[t] = zh;
        int r = tid >> 2, c8 = tid & 3;            // 256 threads: 64 rows x 4 octs
        *reinterpret_cast<f16x8*>(&eT16[r][40 + 8 * c8]) = zh;
    }
    // ---- pair LUT (i<=j triangular; pads clamp to pair (39,39))
    for (int p0 = tid; p0 < 832; p0 += 256) {
        int p = p0 > 819 ? 819 : p0;
        int i = (int)((81.0f - sqrtf(6561.0f - 8.0f * (float)p)) * 0.5f);
        int off = (i * (81 - i)) >> 1;
        if ((((i + 1) * (80 - i)) >> 1) <= p) { ++i; off = (i * (81 - i)) >> 1; }
        else if (off > p)                     { --i; off = (i * (81 - i)) >> 1; }
        lut[p0] = (unsigned short)((i << 8) | (i + (p - off)));
    }

    // ---- gather: coalesced float4 -> f16; write row-major + transposed
    for (int q = tid; q < NF * (KD / 4); q += 256) {
        int i = q >> 4, k4 = q & 15;
        int ix = x[b * NF + i];
        float4 v = reinterpret_cast<const float4*>(V_table + (size_t)ix * KD)[k4];
        f16x4 hv = {(_Float16)v.x, (_Float16)v.y, (_Float16)v.z, (_Float16)v.w};
        *reinterpret_cast<f16x4*>(&e16[i][k4 * 4]) = hv;
        eT16[k4 * 4 + 0][i] = hv[0];
        eT16[k4 * 4 + 1][i] = hv[1];
        eT16[k4 * 4 + 2][i] = hv[2];
        eT16[k4 * 4 + 3][i] = hv[3];
    }
    float linv = (w == 0 && lane < NF) ? lin_table[x[b * NF + lane]] : 0.0f;

    // ---- score constants (32x32x16 form): A = W1 (a x k), D[a,p]
    // A layout: m=a = nt*32 + l31, k = ks*16 + h5*8 + el
    f16x8 Af[2][4];
    #pragma unroll
    for (int nt = 0; nt < 2; ++nt) {
        #pragma unroll
        for (int ks = 0; ks < 4; ++ks) {
            f16x8 t;
            #pragma unroll
            for (int el = 0; el < 8; ++el)
                t[el] = (_Float16)W1[(ks * 16 + h5 * 8 + el) * KD + nt * 32 + l31];
            Af[nt][ks] = t;
        }
    }
    // b1/W2 per owned D-row: a(nt,r) = nt*32 + (r&3) + 8*(r>>2) + 4*h5 (m74 layout)
    f16x8 b1h[2], w2h[2];
    f16x8 b1h2[2], w2h2[2];
    #pragma unroll
    for (int nt = 0; nt < 2; ++nt) {
        f16x8 tb, tw, tb2, tw2;
        #pragma unroll
        for (int e = 0; e < 8; ++e) {
            int r = e;                       // rows 0..7
            int a = nt * 32 + (r & 3) + 8 * (r >> 2) + 4 * h5;
            tb[e] = (_Float16)b1[a];
            tw[e] = (_Float16)W2[a];
            int r2 = e + 8;                  // rows 8..15
            int a2 = nt * 32 + (r2 & 3) + 8 * (r2 >> 2) + 4 * h5;
            tb2[e] = (_Float16)b1[a2];
            tw2[e] = (_Float16)W2[a2];
        }
        b1h[nt] = tb;  w2h[nt] = tw;
        b1h2[nt] = tb2; w2h2[nt] = tw2;
    }
    const float wfv = Wf[w * 16 + l15];
    const float bf0 = bf[0];
    __syncthreads();

    // ---- score GEMM: 26 tiles of 32 pairs; 8 mfma_32x32x16 per tile
    for (int mt = w; mt < 26; mt += 4) {
        const int v = lut[mt * 32 + l31];
        const int i = v >> 8;
        const int j = v & 255;

        f32x16 d0, d1;
        #pragma unroll
        for (int r = 0; r < 8; ++r) {
            d0[r] = (float)b1h[0][r];   d0[r + 8] = (float)b1h2[0][r];
            d1[r] = (float)b1h[1][r];   d1[r + 8] = (float)b1h2[1][r];
        }

        const _Float16* ei = &e16[i][h5 * 8];
        const _Float16* ej = &e16[j][h5 * 8];
        #pragma unroll
        for (int ks = 0; ks < 4; ++ks) {
            f16x8 pw = (*reinterpret_cast<const f16x8*>(ei + ks * 16)) *
                       (*reinterpret_cast<const f16x8*>(ej + ks * 16));
            d0 = __builtin_amdgcn_mfma_f32_32x32x16_f16(Af[0][ks], pw, d0, 0, 0, 0);
            d1 = __builtin_amdgcn_mfma_f32_32x32x16_f16(Af[1][ks], pw, d1, 0, 0, 0);
        }

        float s = 0.0f;
        #pragma unroll
        for (int r = 0; r < 8; ++r) {
            s = fmaf(fmaxf(d0[r], 0.0f),     (float)w2h[0][r],  s);
            s = fmaf(fmaxf(d0[r + 8], 0.0f), (float)w2h2[0][r], s);
            s = fmaf(fmaxf(d1[r], 0.0f),     (float)w2h[1][r],  s);
            s = fmaf(fmaxf(d1[r + 8], 0.0f), (float)w2h2[1][r], s);
        }
        s += __shfl_xor(s, 32, 64);          // other a-half lives in lane^32
        // scores O(+-0.01): exp w/o max-shift safe; softmax shift-invariant.
        float qv = __expf(s);
        if (lane < 32) {
            _Float16 qh = (_Float16)qv;
            Q16[i][j] = qh;                  // mirror write: symmetric scores
            Q16[j][i] = qh;
        }
    }
    __syncthreads();

    // ---- PV, fixed nt = w per wave (16x16x32 form, R18 verbatim)
    const int c = w * 16 + l15;
    const f16x8 bv0 = *reinterpret_cast<const f16x8*>(&eT16[c][lhi * 8]);
    const f16x8 bv1 = *reinterpret_cast<const f16x8*>(&eT16[c][32 + lhi * 8]);
    f16x8 one0, one1;
    #pragma unroll
    for (int el = 0; el < 8; ++el) {
        one0[el] = (_Float16)1.0f;                                // j < 32
        one1[el] = (lhi == 0) ? (_Float16)1.0f : (_Float16)0.0f;  // j 32..39 only
    }

    float acc = 0.0f;
    #pragma unroll
    for (int mt = 0; mt < 3; ++mt) {
        const _Float16* qrow = &Q16[mt * 16 + l15][0];
        f16x8 aq0 = *reinterpret_cast<const f16x8*>(qrow + lhi * 8);
        f16x8 aq1 = *reinterpret_cast<const f16x8*>(qrow + 32 + lhi * 8);

        f32x4 dz = {0.f, 0.f, 0.f, 0.f};
        dz = __builtin_amdgcn_mfma_f32_16x16x32_f16(aq0, one0, dz, 0, 0, 0);
        dz = __builtin_amdgcn_mfma_f32_16x16x32_f16(aq1, one1, dz, 0, 0, 0);

        f32x4 dq = {0.f, 0.f, 0.f, 0.f};
        dq = __builtin_amdgcn_mfma_f32_16x16x32_f16(aq0, bv0, dq, 0, 0, 0);
        dq = __builtin_amdgcn_mfma_f32_16x16x32_f16(aq1, bv1, dq, 0, 0, 0);

        f16x4 ev4 = *reinterpret_cast<const f16x4*>(&eT16[c][mt * 16 + lhi * 4]);
        #pragma unroll
        for (int r = 0; r < 4; ++r) {
            int ii = mt * 16 + lhi * 4 + r;
            float rz = (ii < NF) ? __builtin_amdgcn_rcpf(dz[r]) : 0.0f;
            acc = fmaf((float)ev4[r] * dq[r], rz, acc);  // dq=0 on pad rows
        }
    }

    // ---- inter = sum_c we[c]*Wf[c]; per-wave partial then cross-wave sum
    acc += __shfl_xor(acc, 16, 64);
    acc += __shfl_xor(acc, 32, 64);          // acc = we[c] on all lanes
    float ip = acc * wfv;
    ip += __shfl_xor(ip, 1, 64);
    ip += __shfl_xor(ip, 2, 64);
    ip += __shfl_xor(ip, 4, 64);
    ip += __shfl_xor(ip, 8, 64);
    if (lane == 0) wsum[w] = ip;
    __syncthreads();

    if (w == 0) {
        linv += __shfl_xor(linv, 32, 64);
        linv += __shfl_xor(linv, 16, 64);
        linv += __shfl_xor(linv, 8, 64);
        linv += __shfl_xor(linv, 4, 64);
        linv += __shfl_xor(linv, 2, 64);
        linv += __shfl_xor(linv, 1, 64);
        if (lane == 0) {
            float z = linv + wsum[0] + wsum[1] + wsum[2] + wsum[3] + bf0;
            out[b] = 1.0f / (1.0f + __expf(-z));
        }
    }
}

extern "C" void kernel_launch(void* const* d_in, const int* in_sizes, int n_in,
                              void* d_out, int out_size, void* d_ws, size_t ws_size,
                              hipStream_t stream) {
    const int*   x         = (const int*)d_in[0];
    const float* lin_table = (const float*)d_in[1];
    const float* V_table   = (const float*)d_in[2];
    const float* W1        = (const float*)d_in[3];
    const float* b1        = (const float*)d_in[4];
    const float* W2        = (const float*)d_in[5];
    const float* b2        = (const float*)d_in[6];
    const float* Wf        = (const float*)d_in[7];
    const float* bf        = (const float*)d_in[8];
    float* out = (float*)d_out;

    const int batch = in_sizes[0] / NF;   // 2048
    afm_kernel<<<batch, 256, 0, stream>>>(x, lin_table, V_table, W1, b1, W2, b2,
                                          Wf, bf, out);
}

// Round 23
// 32.635 us; speedup vs baseline: 1.9383x; 1.9383x over previous
//
#include <hip/hip_runtime.h>

#define NF 40
#define KD 64

typedef float f32x4 __attribute__((ext_vector_type(4)));
typedef _Float16 f16x8 __attribute__((ext_vector_type(8)));
typedef _Float16 f16x4 __attribute__((ext_vector_type(4)));

__global__ __launch_bounds__(256, 4)
void afm_kernel(const int* __restrict__ x,
                const float* __restrict__ lin_table,
                const float* __restrict__ V_table,
                const float* __restrict__ W1,
                const float* __restrict__ b1,
                const float* __restrict__ W2,
                const float* __restrict__ b2,
                const float* __restrict__ Wf,
                const float* __restrict__ bf,
                float* __restrict__ out)
{
    // all tiles stride 72 f16 = 144 B (16B-aligned rows, 4-bank/row rotation)
    __shared__ _Float16 e16[NF][72];     // embeddings [field][k]
    __shared__ _Float16 eT16[KD][72];    // transposed [k][field]; cols 40..71 zero
    __shared__ _Float16 Q16[48][72];     // exp(score); fully zero-init (NaN safety)
    __shared__ unsigned short lut[832];  // p -> (i<<8|j)
    __shared__ float wsum[4];

    const int b = blockIdx.x;
    const int tid = threadIdx.x;
    const int w = tid >> 6;
    const int lane = tid & 63;
    const int l15 = lane & 15;
    const int lhi = lane >> 4;

    // ---- zero-init: ALL of Q16 (MFMA A-side NaN safety), eT16 cols 40..71
    {
        f16x8 zh = {0, 0, 0, 0, 0, 0, 0, 0};
        for (int t = tid; t < 48 * 72 / 8; t += 256)
            reinterpret_cast<f16x8*>(&Q16[0][0])[t] = zh;
        int r = tid >> 2, c8 = tid & 3;            // 256 threads: 64 rows x 4 octs
        *reinterpret_cast<f16x8*>(&eT16[r][40 + 8 * c8]) = zh;
    }
    // ---- pair LUT
    for (int p0 = tid; p0 < 832; p0 += 256) {
        int p = p0 > 819 ? 819 : p0;
        int i = (int)((81.0f - sqrtf(6561.0f - 8.0f * (float)p)) * 0.5f);
        int off = (i * (81 - i)) >> 1;
        if ((((i + 1) * (80 - i)) >> 1) <= p) { ++i; off = (i * (81 - i)) >> 1; }
        else if (off > p)                     { --i; off = (i * (81 - i)) >> 1; }
        lut[p0] = (unsigned short)((i << 8) | (i + (p - off)));
    }

    // ---- gather: coalesced float4 -> f16; write row-major + transposed
    for (int q = tid; q < NF * (KD / 4); q += 256) {
        int i = q >> 4, k4 = q & 15;
        int ix = x[b * NF + i];
        float4 v = reinterpret_cast<const float4*>(V_table + (size_t)ix * KD)[k4];
        f16x4 hv = {(_Float16)v.x, (_Float16)v.y, (_Float16)v.z, (_Float16)v.w};
        *reinterpret_cast<f16x4*>(&e16[i][k4 * 4]) = hv;
        eT16[k4 * 4 + 0][i] = hv[0];
        eT16[k4 * 4 + 1][i] = hv[1];
        eT16[k4 * 4 + 2][i] = hv[2];
        eT16[k4 * 4 + 3][i] = hv[3];
    }
    float linv = (w == 0 && lane < NF) ? lin_table[x[b * NF + lane]] : 0.0f;

    // ---- per-lane constants
    f16x8 Af[4][2];
    #pragma unroll
    for (int at = 0; at < 4; ++at) {
        #pragma unroll
        for (int ks = 0; ks < 2; ++ks) {
            f16x8 t;
            #pragma unroll
            for (int el = 0; el < 8; ++el)
                t[el] = (_Float16)W1[(ks * 32 + lhi * 8 + el) * KD + at * 16 + l15];
            Af[at][ks] = t;
        }
    }
    f32x4 b1v[4], w2v[4];
    #pragma unroll
    for (int at = 0; at < 4; ++at) {
        b1v[at] = *reinterpret_cast<const f32x4*>(b1 + at * 16 + lhi * 4);
        w2v[at] = *reinterpret_cast<const f32x4*>(W2 + at * 16 + lhi * 4);
    }
    const float wfv = Wf[w * 16 + l15];
    const float bf0 = bf[0];
    __syncthreads();

    // ---- score GEMM over i<=j pairs (symmetric), 52 tiles of 16 (R18 form)
    const int k0 = lhi * 8;
    for (int mt = w; mt < 52; mt += 4) {
        const int v = lut[mt * 16 + l15];
        const int i = v >> 8;
        const int j = v & 255;
        const _Float16* ei = &e16[i][0];
        const _Float16* ej = &e16[j][0];
        f16x8 B0 = (*reinterpret_cast<const f16x8*>(ei + k0)) *
                   (*reinterpret_cast<const f16x8*>(ej + k0));
        f16x8 B1 = (*reinterpret_cast<const f16x8*>(ei + k0 + 32)) *
                   (*reinterpret_cast<const f16x8*>(ej + k0 + 32));

        f32x4 d[4];
        #pragma unroll
        for (int at = 0; at < 4; ++at) {
            d[at] = b1v[at];
            d[at] = __builtin_amdgcn_mfma_f32_16x16x32_f16(Af[at][0], B0, d[at], 0, 0, 0);
            d[at] = __builtin_amdgcn_mfma_f32_16x16x32_f16(Af[at][1], B1, d[at], 0, 0, 0);
        }
        float s = 0.0f;
        #pragma unroll
        for (int at = 0; at < 4; ++at) {
            #pragma unroll
            for (int r = 0; r < 4; ++r)
                s = fmaf(fmaxf(d[at][r], 0.0f), w2v[at][r], s);
        }
        s += __shfl_xor(s, 16, 64);
        s += __shfl_xor(s, 32, 64);
        // scores O(+-0.01): exp w/o max-shift safe; softmax shift-invariant.
        float qv = __expf(s);
        if (lhi == 0) {
            _Float16 qh = (_Float16)qv;
            Q16[i][j] = qh;                // mirror write: symmetric scores
            Q16[j][i] = qh;
        }
    }
    __syncthreads();

    // ---- PV, fixed nt = w per wave. B-frags hoisted (2 b128, reused 3x).
    // Z in-register via ones-column MFMA; we fused per mt (b64 eT reads).
    const int c = w * 16 + l15;
    const f16x8 bv0 = *reinterpret_cast<const f16x8*>(&eT16[c][lhi * 8]);
    const f16x8 bv1 = *reinterpret_cast<const f16x8*>(&eT16[c][32 + lhi * 8]);
    f16x8 one0, one1;
    #pragma unroll
    for (int el = 0; el < 8; ++el) {
        one0[el] = (_Float16)1.0f;                                // j < 32
        one1[el] = (lhi == 0) ? (_Float16)1.0f : (_Float16)0.0f;  // j 32..39 only
    }

    float acc = 0.0f;
    #pragma unroll
    for (int mt = 0; mt < 3; ++mt) {
        const _Float16* qrow = &Q16[mt * 16 + l15][0];
        f16x8 aq0 = *reinterpret_cast<const f16x8*>(qrow + lhi * 8);
        f16x8 aq1 = *reinterpret_cast<const f16x8*>(qrow + 32 + lhi * 8);

        f32x4 dz = {0.f, 0.f, 0.f, 0.f};
        dz = __builtin_amdgcn_mfma_f32_16x16x32_f16(aq0, one0, dz, 0, 0, 0);
        dz = __builtin_amdgcn_mfma_f32_16x16x32_f16(aq1, one1, dz, 0, 0, 0);

        f32x4 dq = {0.f, 0.f, 0.f, 0.f};
        dq = __builtin_amdgcn_mfma_f32_16x16x32_f16(aq0, bv0, dq, 0, 0, 0);
        dq = __builtin_amdgcn_mfma_f32_16x16x32_f16(aq1, bv1, dq, 0, 0, 0);

        f16x4 ev4 = *reinterpret_cast<const f16x4*>(&eT16[c][mt * 16 + lhi * 4]);
        #pragma unroll
        for (int r = 0; r < 4; ++r) {
            int ii = mt * 16 + lhi * 4 + r;
            float rz = (ii < NF) ? __builtin_amdgcn_rcpf(dz[r]) : 0.0f;
            acc = fmaf((float)ev4[r] * dq[r], rz, acc);  // dq=0 on pad rows
        }
    }

    // ---- inter = sum_c we[c]*Wf[c]; per-wave partial then cross-wave sum
    acc += __shfl_xor(acc, 16, 64);
    acc += __shfl_xor(acc, 32, 64);          // acc = we[c] on all lanes
    float ip = acc * wfv;
    ip += __shfl_xor(ip, 1, 64);
    ip += __shfl_xor(ip, 2, 64);
    ip += __shfl_xor(ip, 4, 64);
    ip += __shfl_xor(ip, 8, 64);
    if (lane == 0) wsum[w] = ip;
    __syncthreads();

    if (w == 0) {
        linv += __shfl_xor(linv, 32, 64);
        linv += __shfl_xor(linv, 16, 64);
        linv += __shfl_xor(linv, 8, 64);
        linv += __shfl_xor(linv, 4, 64);
        linv += __shfl_xor(linv, 2, 64);
        linv += __shfl_xor(linv, 1, 64);
        if (lane == 0) {
            float z = linv + wsum[0] + wsum[1] + wsum[2] + wsum[3] + bf0;
            out[b] = 1.0f / (1.0f + __expf(-z));
        }
    }
}

extern "C" void kernel_launch(void* const* d_in, const int* in_sizes, int n_in,
                              void* d_out, int out_size, void* d_ws, size_t ws_size,
                              hipStream_t stream) {
    const int*   x         = (const int*)d_in[0];
    const float* lin_table = (const float*)d_in[1];
    const float* V_table   = (const float*)d_in[2];
    const float* W1        = (const float*)d_in[3];
    const float* b1        = (const float*)d_in[4];
    const float* W2        = (const float*)d_in[5];
    const float* b2        = (const float*)d_in[6];
    const float* Wf        = (const float*)d_in[7];
    const float* bf        = (const float*)d_in[8];
    float* out = (float*)d_out;

    const int batch = in_sizes[0] / NF;   // 2048
    afm_kernel<<<batch, 256, 0, stream>>>(x, lin_table, V_table, W1, b1, W2, b2,
                                          Wf, bf, out);
}